// Round 17
// baseline (95.258 us; speedup 1.0000x reference)
//
#include <hip/hip_runtime.h>
#include <cmath>

#define BN 32
#define AN 32768
#define GN 64
#define TPB 256                    // k_fused threads per block
#define APT 4                      // anchors per thread
#define ANCH_PER_BLK (TPB * APT)   // 1024
#define FBLK (AN / ANCH_PER_BLK)   // 32 k_fused blocks per image
#define SBLK 8                     // k_scan blocks per image
#define CAP 8192                   // survivor capacity per image

// ---------------- workspace layout (bytes) ----------------
// 0    : int totN ; 4: float totL ; 8: float totPC ; 12: uint done
// 64   : int   num_pos[32]   (bit7-positives only)
// 192  : float locs[32]
// 320  : float pcs[32]
// 448  : float negacc[32]
// 576  : uint  scnt[32]
// 704  : int   fnum[32]
// 832  : uint2 selinfo[32]
// 1280 : u64   gkey[B*G]        (16 KB, atomicMax)
// 17664   : u32 hist1[B][4096]  (512 KB, atomicAdd)
// 541952  : u8  abyte[B*A]      (1 MB, fully overwritten)
// 1590528 : f32 surv[B][CAP]    (1 MB, gated by scnt)
#define WS_TOTN(ws)    ((int*)(ws))
#define WS_TOTL(ws)    ((float*)((char*)(ws) + 4))
#define WS_TOTPC(ws)   ((float*)((char*)(ws) + 8))
#define WS_DONE(ws)    ((unsigned*)((char*)(ws) + 12))
#define WS_NUMPOS(ws)  ((int*)((char*)(ws) + 64))
#define WS_LOCS(ws)    ((float*)((char*)(ws) + 192))
#define WS_PCS(ws)     ((float*)((char*)(ws) + 320))
#define WS_NEGACC(ws)  ((float*)((char*)(ws) + 448))
#define WS_SCNT(ws)    ((unsigned*)((char*)(ws) + 576))
#define WS_FNUM(ws)    ((int*)((char*)(ws) + 704))
#define WS_SELINFO(ws) ((uint2*)((char*)(ws) + 832))
#define WS_GKEY(ws)    ((unsigned long long*)((char*)(ws) + 1280))
#define WS_HIST1(ws)   ((unsigned*)((char*)(ws) + 17664))
#define WS_ABYTE(ws)   ((unsigned char*)((char*)(ws) + 541952))
#define WS_SURV(ws)    ((float*)((char*)(ws) + 1590528))
#define WS_ZERO_WORDS  (541952 / 4)     // scalars + gkey + hist1

#define LN2F 0.69314718056f

__device__ __forceinline__ float negloss(float p) {
    // -log(1-p); MUST be bit-identical in every kernel (histogram bins).
    return -fmaxf(__log2f(1.0f - p) * LN2F, -100.0f);
}
__device__ __forceinline__ float posbce(float p) {
    return -fmaxf(__log2f(p) * LN2F, -100.0f);
}
__device__ __forceinline__ float smoothl1(float4 bb, float4 m) {
    float d0 = (bb.x + bb.z) * 0.5f - m.x;
    float d1 = (bb.y + bb.w) * 0.5f - m.y;
    float d2 = (bb.z - bb.x) - m.z;
    float d3 = (bb.w - bb.y) - m.w;
    float ad = fabsf(d0); float s = (ad < 1.0f) ? 0.5f * d0 * d0 : ad - 0.5f;
    ad = fabsf(d1); s += (ad < 1.0f) ? 0.5f * d1 * d1 : ad - 0.5f;
    ad = fabsf(d2); s += (ad < 1.0f) ? 0.5f * d2 * d2 : ad - 0.5f;
    ad = fabsf(d3); s += (ad < 1.0f) ? 0.5f * d3 * d3 : ad - 0.5f;
    return s;
}

// ===================== k_init =====================
__global__ __launch_bounds__(256) void k_init(unsigned* __restrict__ ws) {
    unsigned gid = blockIdx.x * 256 + threadIdx.x;
    for (unsigned i = gid; i < WS_ZERO_WORDS; i += 128 * 256) ws[i] = 0u;
}

// ===================== k_fused: IoU + argmaxes + prep (APT=4) =====================
// Per-j fixed costs (gt b128 read, area calc, key+merge+atomic, loop overhead)
// amortized over 4 anchors. Area computed from corners (bit-identical, kills
// the b32 read). Merge order a0<a1<a2<a3, strict > -> exact min-idx ties.
__global__ __launch_bounds__(TPB, 8) void k_fused(const float* __restrict__ anchors,
                                                  const float* __restrict__ gt,
                                                  const float* __restrict__ bbox,
                                                  const float* __restrict__ conf,
                                                  unsigned long long* __restrict__ gkey,
                                                  unsigned char* __restrict__ abyte,
                                                  unsigned* __restrict__ hist1,
                                                  int* __restrict__ num_pos,
                                                  float* __restrict__ locs,
                                                  float* __restrict__ pcs) {
    __shared__ float4 sgt4[128];                 // duplicated corners (16B aligned)
    __shared__ float4 sgcs[GN];
    __shared__ unsigned long long skey2[128];    // flat, idx-addressed
    __shared__ unsigned hist[2048];              // 8 KB: bins i and i+2048 packed u16
    __shared__ float redL[4], redP[4];
    __shared__ int   redN[4];

    int b = blockIdx.y;
    int tid = threadIdx.x;
    int lane = tid & 63;
    int wave = tid >> 6;
    int blockbase = blockIdx.x * ANCH_PER_BLK;

    for (int i = tid; i < 2048; i += TPB) hist[i] = 0;
    if (tid < GN) {
        float4 g = ((const float4*)gt)[b * GN + tid];
        sgt4[tid] = g; sgt4[tid + 64] = g;
        sgcs[tid] = make_float4((g.x + g.z) * 0.5f, (g.y + g.w) * 0.5f,
                                g.z - g.x, g.w - g.y);
        skey2[tid] = 0ull; skey2[tid + 64] = 0ull;
    }
    __syncthreads();

    unsigned aidx[APT];
    unsigned naidx[APT];
    float4 ab[APT];
    float  sa[APT];
    float  bv[APT];
    int    bi[APT];
#pragma unroll
    for (int q = 0; q < APT; ++q) {
        aidx[q] = (unsigned)(blockbase + q * TPB + tid);
        naidx[q] = ~aidx[q];
        ab[q] = ((const float4*)anchors)[aidx[q]];
        sa[q] = (ab[q].z - ab[q].x) * (ab[q].w - ab[q].y) + 1e-6f;
        bv[q] = -1.0f;
        bi[q] = 0;
    }

#pragma unroll 8
    for (int j = 0; j < GN; ++j) {
        int idx = lane + j;                  // 0..126, duplicated table (no wrap)
        float4 gq = sgt4[idx];               // 1 x ds_read_b128
        float gA = (gq.z - gq.x) * (gq.w - gq.y);   // bit-identical to stored area

        float v[APT];
#pragma unroll
        for (int q = 0; q < APT; ++q) {
            float iw = fminf(ab[q].z, gq.z) - fmaxf(ab[q].x, gq.x);
            float ih = fminf(ab[q].w, gq.w) - fmaxf(ab[q].y, gq.y);
            float inr = fmaxf(iw, 0.0f) * fmaxf(ih, 0.0f);
            v[q] = inr * __builtin_amdgcn_rcpf((sa[q] + gA) - inr);
            if (v[q] > bv[q]) { bv[q] = v[q]; bi[q] = idx; }
        }

        // per-gt 4->1 merge (ascending anchor idx; strict > keeps min idx on ties)
        float vm = v[0]; unsigned nam = naidx[0];
        if (v[1] > vm) { vm = v[1]; nam = naidx[1]; }
        if (v[2] > vm) { vm = v[2]; nam = naidx[2]; }
        if (v[3] > vm) { vm = v[3]; nam = naidx[3]; }
        unsigned long long key = ((unsigned long long)__float_as_uint(vm) << 32)
                               | (unsigned long long)nam;
        atomicMax(&skey2[idx], key);                 // imm-offset ds_max under unroll
    }
    __syncthreads();

    size_t base = (size_t)b * AN;
    float locv = 0.0f, pcv = 0.0f;
    int npv = 0;
#pragma unroll
    for (int q = 0; q < APT; ++q) {
        unsigned gq = (unsigned)bi[q] & 63u;
        bool posq = bv[q] > 0.5f;
        abyte[base + aidx[q]] = (unsigned char)((posq ? 0x80u : 0u) | gq);
        float p = conf[base + aidx[q]];
        if (posq) {
            locv += smoothl1(((const float4*)bbox)[base + aidx[q]], sgcs[gq]);
            pcv += posbce(p); npv += 1;
        } else {
            unsigned bin = __float_as_uint(negloss(p)) >> 20;
            atomicAdd(&hist[bin & 2047u], 1u << ((bin >> 11) << 4));
        }
    }

    if (tid < GN) {
        unsigned long long m0 = skey2[tid];
        unsigned long long m1 = skey2[tid + 64];     // same gt, rotated wrap half
        atomicMax(&gkey[b * GN + tid], (m0 > m1) ? m0 : m1);
    }

    for (int off = 32; off; off >>= 1) {
        locv += __shfl_xor(locv, off);
        pcv  += __shfl_xor(pcv, off);
        npv  += __shfl_xor(npv, off);
    }
    if (lane == 0) { redL[wave] = locv; redP[wave] = pcv; redN[wave] = npv; }
    __syncthreads();
    if (tid == 0) {
        float L = redL[0] + redL[1] + redL[2] + redL[3];
        float P = redP[0] + redP[1] + redP[2] + redP[3];
        int   N = redN[0] + redN[1] + redN[2] + redN[3];
        if (N) atomicAdd(&num_pos[b], N);
        atomicAdd(&locs[b], L);
        atomicAdd(&pcs[b], P);
    }
    // flush packed hist -> global 4096-bin u32 hist1 (exact counts)
    for (int i = tid; i < 2048; i += TPB) {
        unsigned w = hist[i];
        unsigned c0 = w & 0xFFFFu, c1 = w >> 16;
        if (c0) atomicAdd(&hist1[b * 4096 + i], c0);
        if (c1) atomicAdd(&hist1[b * 4096 + i + 2048], c1);
    }
}

// ===================== k_scan: distributed tail (r16, unchanged) =====================
__global__ __launch_bounds__(1024) void k_scan(const float* __restrict__ bbox,
                                               const float* __restrict__ conf,
                                               const float* __restrict__ gt,
                                               const unsigned char* __restrict__ abyte,
                                               const unsigned long long* __restrict__ gkey,
                                               const unsigned* __restrict__ hist1,
                                               const int* __restrict__ num_pos,
                                               int* __restrict__ totN,
                                               float* __restrict__ totL,
                                               float* __restrict__ totPC,
                                               float* __restrict__ negacc,
                                               unsigned* __restrict__ scnt,
                                               uint2* __restrict__ selinfo,
                                               int* __restrict__ fnum,
                                               float* __restrict__ surv) {
    __shared__ unsigned hist[4096];     // 16 KB
    __shared__ float scomp[4096];       // 16 KB survivor staging
    __shared__ unsigned bitmap[128];
    __shared__ float4 sgcs[GN];
    __shared__ unsigned sforced[GN];
    __shared__ float redA[16];
    __shared__ unsigned s_c, s_base, s_sel, s_krem, s_k;

    int blk = blockIdx.x, b = blockIdx.y, tid = threadIdx.x;
    int lane = tid & 63, wave = tid >> 6;

    for (int i = tid; i < 4096; i += 1024) hist[i] = hist1[b * 4096 + i];
    if (tid < 128) bitmap[tid] = 0;
    if (tid == 0) s_c = 0;
    if (tid < GN) {
        float4 g = ((const float4*)gt)[b * GN + tid];
        sgcs[tid] = make_float4((g.x + g.z) * 0.5f, (g.y + g.w) * 0.5f,
                                g.z - g.x, g.w - g.y);
    }
    __syncthreads();

    if (tid < GN) {
        unsigned a = ~(unsigned)(gkey[b * GN + tid] & 0xFFFFFFFFull);
        sforced[tid] = a;
        if ((int)(a >> 12) == blk)
            atomicOr(&bitmap[(a & 4095u) >> 5], 1u << (a & 31u));
    }
    __syncthreads();

    // forced corrections + np + k (wave 0; deterministic, redundant per block)
    if (tid < GN) {
        unsigned a = sforced[tid];
        bool own = true;
        for (int t = 0; t < tid; ++t) if (sforced[t] == a) { own = false; break; }
        int fn = 0; float fl = 0.0f, fp = 0.0f;
        if (own) {
            unsigned by = abyte[(size_t)b * AN + a];
            if (!(by & 0x80u)) {
                float p = conf[(size_t)b * AN + a];
                atomicAdd(&hist[__float_as_uint(negloss(p)) >> 20], 0xFFFFFFFFu);
                fn = 1; fp = posbce(p);
                fl = smoothl1(((const float4*)bbox)[(size_t)b * AN + a], sgcs[by & 63u]);
            }
        }
        for (int off = 32; off; off >>= 1) {
            fn += __shfl_xor(fn, off);
            fl += __shfl_xor(fl, off);
            fp += __shfl_xor(fp, off);
        }
        int np = num_pos[b] + fn;
        unsigned k = (unsigned)min(3 * np, AN - np);
        if (tid == 0) {
            s_k = k;
            if (blk == 0) {
                fnum[b] = fn;
                if (fn) atomicAdd(totN, fn);
                atomicAdd(totL, fl);
                atomicAdd(totPC, fp);
            }
        }
    }
    __syncthreads();
    unsigned k = s_k;
    if (k == 0) return;                    // negacc/scnt stay 0

    // round-1 select over corrected hist (two-level wave scan)
    if (tid < 64) {
        unsigned c = 0;
        int base = tid * 64;
#pragma unroll
        for (int i = 0; i < 64; ++i) c += hist[base + ((tid + i) & 63)];   // rotated
        unsigned S = c;
#pragma unroll
        for (int d = 1; d < 64; d <<= 1) { unsigned t = __shfl_down(S, d); if (tid + d < 64) S += t; }
        unsigned E = S - c;
        unsigned long long mk = __ballot(E < k && k <= S);
        int bl = __ffsll(mk) - 1;
        unsigned kin = k - __shfl(E, bl);
        unsigned h = hist[bl * 64 + tid];
        unsigned S2 = h;
#pragma unroll
        for (int d = 1; d < 64; d <<= 1) { unsigned t = __shfl_down(S2, d); if (tid + d < 64) S2 += t; }
        unsigned E2 = S2 - h;
        unsigned long long mk2 = __ballot(E2 < kin && kin <= S2);
        int bin_l = __ffsll(mk2) - 1;
        unsigned E2b = __shfl(E2, bin_l);
        if (tid == 0) { s_sel = (unsigned)(bl * 64 + bin_l); s_krem = kin - E2b; }
    }
    __syncthreads();
    unsigned sel1 = s_sel;
    if (blk == 0 && tid == 0) selinfo[b] = make_uint2(s_sel, s_krem);

    // stream own 4096 anchors: strictly-above sum + boundary compaction
    size_t ibase = (size_t)b * AN + blk * 4096;
    float4 c4 = ((const float4*)conf)[(ibase >> 2) + tid];
    uchar4 u4 = ((const uchar4*)abyte)[(ibase >> 2) + tid];
    int li = tid * 4;
    unsigned fb = (bitmap[li >> 5] >> (li & 31)) & 0xFu;
    float cc[4] = {c4.x, c4.y, c4.z, c4.w};
    unsigned by[4] = {u4.x, u4.y, u4.z, u4.w};
    float acc = 0.0f;
#pragma unroll
    for (int e = 0; e < 4; ++e) {
        bool pos = (by[e] & 0x80u) || ((fb >> e) & 1u);
        if (!pos) {
            float v = negloss(cc[e]);
            unsigned bin = __float_as_uint(v) >> 20;
            if (bin > sel1) acc += v;
            else if (bin == sel1) {
                unsigned p = atomicAdd(&s_c, 1u);   // LDS atomic
                scomp[p] = v;                        // <=4096 per block
            }
        }
    }
    for (int off = 32; off; off >>= 1) acc += __shfl_xor(acc, off);
    if (lane == 0) redA[wave] = acc;
    __syncthreads();
    if (tid == 0) {
        float t = 0.0f;
        for (int w = 0; w < 16; ++w) t += redA[w];
        atomicAdd(&negacc[b], t);
        s_base = atomicAdd(&scnt[b], s_c);          // one reservation per block
    }
    __syncthreads();
    unsigned cnt = s_c, base2 = s_base;
    for (unsigned i = tid; i < cnt; i += 1024)
        if (base2 + i < CAP) surv[(size_t)b * CAP + base2 + i] = scomp[i];
}

// ===================== k_fin: resolve low 20 bits + finalize (r16, unchanged) =====================
__global__ __launch_bounds__(1024) void k_fin(const float* __restrict__ surv,
                                              const unsigned* __restrict__ scnt,
                                              const uint2* __restrict__ selinfo,
                                              const int* __restrict__ num_pos,
                                              const int* __restrict__ fnum,
                                              const float* __restrict__ locs,
                                              const float* __restrict__ pcs,
                                              const float* __restrict__ negacc,
                                              int* __restrict__ totN,
                                              float* __restrict__ totL,
                                              float* __restrict__ totPC,
                                              unsigned* __restrict__ done,
                                              float* __restrict__ out) {
    __shared__ float sv[CAP];           // 32 KB
    __shared__ unsigned hist[4096];     // 16 KB
    __shared__ float redA[16];
    __shared__ unsigned s_sel, s_krem;

    int b = blockIdx.x, tid = threadIdx.x;
    int lane = tid & 63, wave = tid >> 6;

    int np = num_pos[b] + fnum[b];
    unsigned k = (unsigned)min(3 * np, AN - np);
    float nc = 0.0f;

    if (k > 0) {
        uint2 si = selinfo[b];
        unsigned krem1 = si.y;
        unsigned n = min(scnt[b], (unsigned)CAP);
        for (unsigned i = tid; i < n; i += 1024) sv[i] = surv[(size_t)b * CAP + i];
        for (int i = tid; i < 4096; i += 1024) hist[i] = 0;
        __syncthreads();

        // round A: 12 bits (key>>8)&0xFFF
        for (unsigned i = tid; i < n; i += 1024)
            atomicAdd(&hist[(__float_as_uint(sv[i]) >> 8) & 0xFFFu], 1u);
        __syncthreads();
        if (tid < 64) {
            unsigned c = 0;
            int base = tid * 64;
#pragma unroll
            for (int i = 0; i < 64; ++i) c += hist[base + ((tid + i) & 63)];
            unsigned S = c;
#pragma unroll
            for (int d = 1; d < 64; d <<= 1) { unsigned t = __shfl_down(S, d); if (tid + d < 64) S += t; }
            unsigned E = S - c;
            unsigned long long mk = __ballot(E < krem1 && krem1 <= S);
            int bl = __ffsll(mk) - 1;
            unsigned kin = krem1 - __shfl(E, bl);
            unsigned h = hist[bl * 64 + tid];
            unsigned S2 = h;
#pragma unroll
            for (int d = 1; d < 64; d <<= 1) { unsigned t = __shfl_down(S2, d); if (tid + d < 64) S2 += t; }
            unsigned E2 = S2 - h;
            unsigned long long mk2 = __ballot(E2 < kin && kin <= S2);
            int bin_l = __ffsll(mk2) - 1;
            unsigned E2b = __shfl(E2, bin_l);
            if (tid == 0) { s_sel = (unsigned)(bl * 64 + bin_l); s_krem = kin - E2b; }
        }
        __syncthreads();
        unsigned selA = s_sel, krem2 = s_krem;
        __syncthreads();
        if (tid < 256) hist[tid] = 0;
        __syncthreads();

        // round B: low 8 bits, masked to selA
        for (unsigned i = tid; i < n; i += 1024) {
            unsigned key = __float_as_uint(sv[i]);
            if (((key >> 8) & 0xFFFu) == selA) atomicAdd(&hist[key & 0xFFu], 1u);
        }
        __syncthreads();
        if (tid < 64) {
            int base = tid * 4;
            unsigned c = 0;
#pragma unroll
            for (int i = 0; i < 4; ++i) c += hist[base + i];
            unsigned S = c;
#pragma unroll
            for (int d = 1; d < 64; d <<= 1) { unsigned t = __shfl_down(S, d); if (tid + d < 64) S += t; }
            unsigned E = S - c;
            unsigned long long mk = __ballot(E < krem2 && krem2 <= S);
            int bl = __ffsll(mk) - 1;
            if (tid == bl) {
                unsigned cum = E;
                for (int bin = base + 3; bin >= base; --bin) {
                    unsigned h = hist[bin];
                    cum += h;
                    if (cum >= krem2) { s_sel = (unsigned)bin; s_krem = krem2 - (cum - h); break; }
                }
            }
        }
        __syncthreads();
        unsigned Tkey = (si.x << 20) | (selA << 8) | s_sel;
        unsigned kremF = s_krem;
        float T = __uint_as_float(Tkey);

        float part = 0.0f;
        for (unsigned i = tid; i < n; i += 1024)
            if (__float_as_uint(sv[i]) > Tkey) part += sv[i];
        for (int off = 32; off; off >>= 1) part += __shfl_xor(part, off);
        if (lane == 0) redA[wave] = part;
        __syncthreads();
        if (tid == 0) {
            float t = 0.0f;
            for (int w = 0; w < 16; ++w) t += redA[w];
            nc = negacc[b] + t + (float)kremF * T;
        }
    }

    if (tid == 0) {
        atomicAdd(totN, num_pos[b]);        // fn was added by k_scan blk0
        atomicAdd(totL, locs[b]);
        atomicAdd(totPC, pcs[b] + nc);
        __threadfence();
        unsigned old = atomicAdd(done, 1u);
        if (old == BN - 1) {
            int   N  = atomicAdd(totN, 0);
            float L  = atomicAdd(totL, 0.0f);
            float PC = atomicAdd(totPC, 0.0f);
            float tp = (float)max(1, N);
            float loc_loss = L / tp;
            float conf_loss = PC / tp;
            out[0] = loc_loss + conf_loss;
            out[1] = conf_loss;
            out[2] = loc_loss;
        }
    }
}

extern "C" void kernel_launch(void* const* d_in, const int* in_sizes, int n_in,
                              void* d_out, int out_size, void* d_ws, size_t ws_size,
                              hipStream_t stream) {
    const float* bbox    = (const float*)d_in[0];   // [B,A,4]
    const float* conf    = (const float*)d_in[1];   // [B,A]
    const float* anchors = (const float*)d_in[2];   // [A,4]
    const float* gt      = (const float*)d_in[3];   // [B,G,4]
    float* out = (float*)d_out;

    k_init<<<128, 256, 0, stream>>>((unsigned*)d_ws);

    dim3 g1(FBLK, BN);                // (32, 32) = 1024 blocks, 4 anchors/thread
    k_fused<<<g1, TPB, 0, stream>>>(anchors, gt, bbox, conf,
                                    WS_GKEY(d_ws), WS_ABYTE(d_ws), WS_HIST1(d_ws),
                                    WS_NUMPOS(d_ws), WS_LOCS(d_ws), WS_PCS(d_ws));

    dim3 g2(SBLK, BN);                // 256 blocks
    k_scan<<<g2, 1024, 0, stream>>>(bbox, conf, gt, WS_ABYTE(d_ws), WS_GKEY(d_ws),
                                    WS_HIST1(d_ws), WS_NUMPOS(d_ws),
                                    WS_TOTN(d_ws), WS_TOTL(d_ws), WS_TOTPC(d_ws),
                                    WS_NEGACC(d_ws), WS_SCNT(d_ws), WS_SELINFO(d_ws),
                                    WS_FNUM(d_ws), WS_SURV(d_ws));

    k_fin<<<BN, 1024, 0, stream>>>(WS_SURV(d_ws), WS_SCNT(d_ws), WS_SELINFO(d_ws),
                                   WS_NUMPOS(d_ws), WS_FNUM(d_ws), WS_LOCS(d_ws),
                                   WS_PCS(d_ws), WS_NEGACC(d_ws),
                                   WS_TOTN(d_ws), WS_TOTL(d_ws), WS_TOTPC(d_ws),
                                   WS_DONE(d_ws), out);
}

// Round 18
// 68.206 us; speedup vs baseline: 1.3966x; 1.3966x over previous
//
#include <hip/hip_runtime.h>
#include <cmath>

#define BN 32
#define AN 32768
#define GN 64
#define TPB 256                    // k_fused threads per block
#define ANCH_PER_BLK 512           // 2 anchors per thread
#define FBLK 64                    // k_fused blocks per image
#define SBLK 8                     // k_scan blocks per image
#define CAP 8192                   // survivor capacity per image

// ---------------- workspace layout (bytes) ----------------
// 0    : int totN ; 4: float totL ; 8: float totPC ; 12: uint done
// 64   : int   num_pos[32]   (bit7-positives only)
// 192  : float locs[32]
// 320  : float pcs[32]
// 448  : float negacc[32]
// 576  : uint  scnt[32]
// 704  : int   fnum[32]
// 832  : uint2 selinfo[32]
// 1280 : u64   gkey[B*G]        (16 KB, atomicMax)
// 17664   : u32 hist1[B][4096]  (512 KB, atomicAdd)
// 541952  : u8  abyte[B*A]      (1 MB, fully overwritten)
// 1590528 : f32 surv[B][CAP]    (1 MB, gated by scnt)
#define WS_TOTN(ws)    ((int*)(ws))
#define WS_TOTL(ws)    ((float*)((char*)(ws) + 4))
#define WS_TOTPC(ws)   ((float*)((char*)(ws) + 8))
#define WS_DONE(ws)    ((unsigned*)((char*)(ws) + 12))
#define WS_NUMPOS(ws)  ((int*)((char*)(ws) + 64))
#define WS_LOCS(ws)    ((float*)((char*)(ws) + 192))
#define WS_PCS(ws)     ((float*)((char*)(ws) + 320))
#define WS_NEGACC(ws)  ((float*)((char*)(ws) + 448))
#define WS_SCNT(ws)    ((unsigned*)((char*)(ws) + 576))
#define WS_FNUM(ws)    ((int*)((char*)(ws) + 704))
#define WS_SELINFO(ws) ((uint2*)((char*)(ws) + 832))
#define WS_GKEY(ws)    ((unsigned long long*)((char*)(ws) + 1280))
#define WS_HIST1(ws)   ((unsigned*)((char*)(ws) + 17664))
#define WS_ABYTE(ws)   ((unsigned char*)((char*)(ws) + 541952))
#define WS_SURV(ws)    ((float*)((char*)(ws) + 1590528))
#define WS_ZERO_WORDS  (541952 / 4)     // scalars + gkey + hist1

#define LN2F 0.69314718056f

__device__ __forceinline__ float negloss(float p) {
    // -log(1-p); MUST be bit-identical in every kernel (histogram bins).
    return -fmaxf(__log2f(1.0f - p) * LN2F, -100.0f);
}
__device__ __forceinline__ float posbce(float p) {
    return -fmaxf(__log2f(p) * LN2F, -100.0f);
}
__device__ __forceinline__ float smoothl1(float4 bb, float4 m) {
    float d0 = (bb.x + bb.z) * 0.5f - m.x;
    float d1 = (bb.y + bb.w) * 0.5f - m.y;
    float d2 = (bb.z - bb.x) - m.z;
    float d3 = (bb.w - bb.y) - m.w;
    float ad = fabsf(d0); float s = (ad < 1.0f) ? 0.5f * d0 * d0 : ad - 0.5f;
    ad = fabsf(d1); s += (ad < 1.0f) ? 0.5f * d1 * d1 : ad - 0.5f;
    ad = fabsf(d2); s += (ad < 1.0f) ? 0.5f * d2 * d2 : ad - 0.5f;
    ad = fabsf(d3); s += (ad < 1.0f) ? 0.5f * d3 * d3 : ad - 0.5f;
    return s;
}

// ===================== k_init =====================
__global__ __launch_bounds__(256) void k_init(unsigned* __restrict__ ws) {
    unsigned gid = blockIdx.x * 256 + threadIdx.x;
    for (unsigned i = gid; i < WS_ZERO_WORDS; i += 128 * 256) ws[i] = 0u;
}

// ===================== k_fused: IoU + argmaxes + prep (r16 proven) =====================
//  (a) corners packed float4 -> 1 ds_read_b128 per j;
//  (b) hist packed 2x u16 per u32 word -> 8 KB LDS; total ~13 KB -> 8 blocks/CU.
__global__ __launch_bounds__(TPB, 8) void k_fused(const float* __restrict__ anchors,
                                                  const float* __restrict__ gt,
                                                  const float* __restrict__ bbox,
                                                  const float* __restrict__ conf,
                                                  unsigned long long* __restrict__ gkey,
                                                  unsigned char* __restrict__ abyte,
                                                  unsigned* __restrict__ hist1,
                                                  int* __restrict__ num_pos,
                                                  float* __restrict__ locs,
                                                  float* __restrict__ pcs) {
    __shared__ float4 sgt4[128];                 // duplicated corners (16B aligned)
    __shared__ float  sga[128];                  // duplicated areas
    __shared__ float4 sgcs[GN];
    __shared__ unsigned long long skey2[128];    // flat, idx-addressed
    __shared__ unsigned hist[2048];              // 8 KB: bins i and i+2048 packed u16
    __shared__ float redL[4], redP[4];
    __shared__ int   redN[4];

    int b = blockIdx.y;
    int tid = threadIdx.x;
    int lane = tid & 63;
    int wave = tid >> 6;
    int blockbase = blockIdx.x * ANCH_PER_BLK;

    for (int i = tid; i < 2048; i += TPB) hist[i] = 0;
    if (tid < GN) {
        float4 g = ((const float4*)gt)[b * GN + tid];
        float area = (g.z - g.x) * (g.w - g.y);
        sgt4[tid] = g; sgt4[tid + 64] = g;
        sga[tid]  = area; sga[tid + 64] = area;
        sgcs[tid] = make_float4((g.x + g.z) * 0.5f, (g.y + g.w) * 0.5f,
                                g.z - g.x, g.w - g.y);
        skey2[tid] = 0ull; skey2[tid + 64] = 0ull;
    }
    __syncthreads();

    unsigned a0 = (unsigned)(blockbase + tid);
    unsigned a1 = a0 + TPB;
    float4 ab0 = ((const float4*)anchors)[a0];
    float4 ab1 = ((const float4*)anchors)[a1];
    float sa0 = (ab0.z - ab0.x) * (ab0.w - ab0.y) + 1e-6f;
    float sa1 = (ab1.z - ab1.x) * (ab1.w - ab1.y) + 1e-6f;
    unsigned na0 = ~a0, na1 = ~a1;

    float bv0 = -1.0f, bv1 = -1.0f;
    int bi0 = 0, bi1 = 0;

#pragma unroll 8
    for (int j = 0; j < GN; ++j) {
        int idx = lane + j;                  // 0..126, duplicated tables (no wrap)
        float4 gq = sgt4[idx];               // 1 x ds_read_b128
        float gA  = sga[idx];                // 1 x ds_read_b32

        float iw0 = fminf(ab0.z, gq.z) - fmaxf(ab0.x, gq.x);
        float ih0 = fminf(ab0.w, gq.w) - fmaxf(ab0.y, gq.y);
        float in0 = fmaxf(iw0, 0.0f) * fmaxf(ih0, 0.0f);
        float v0 = in0 * __builtin_amdgcn_rcpf((sa0 + gA) - in0);

        float iw1 = fminf(ab1.z, gq.z) - fmaxf(ab1.x, gq.x);
        float ih1 = fminf(ab1.w, gq.w) - fmaxf(ab1.y, gq.y);
        float in1 = fmaxf(iw1, 0.0f) * fmaxf(ih1, 0.0f);
        float v1 = in1 * __builtin_amdgcn_rcpf((sa1 + gA) - in1);

        if (v0 > bv0) { bv0 = v0; bi0 = idx; }
        if (v1 > bv1) { bv1 = v1; bi1 = idx; }

        float vm = v0; unsigned nam = na0;           // a0 < a1: min idx on ties
        if (v1 > vm) { vm = v1; nam = na1; }
        unsigned long long key = ((unsigned long long)__float_as_uint(vm) << 32)
                               | (unsigned long long)nam;
        atomicMax(&skey2[idx], key);                 // imm-offset ds_max under unroll
    }
    __syncthreads();

    size_t base = (size_t)b * AN;
    unsigned g0 = (unsigned)bi0 & 63u, g1 = (unsigned)bi1 & 63u;
    bool pos0 = bv0 > 0.5f, pos1 = bv1 > 0.5f;
    abyte[base + a0] = (unsigned char)((pos0 ? 0x80u : 0u) | g0);
    abyte[base + a1] = (unsigned char)((pos1 ? 0x80u : 0u) | g1);

    if (tid < GN) {
        unsigned long long m0 = skey2[tid];
        unsigned long long m1 = skey2[tid + 64];     // same gt, rotated wrap half
        atomicMax(&gkey[b * GN + tid], (m0 > m1) ? m0 : m1);
    }

    // ---- prep: conf, pos scalars, negloss hist (packed u16 pairs)
    float p0 = conf[base + a0];
    float p1 = conf[base + a1];
    float locv = 0.0f, pcv = 0.0f;
    int npv = 0;
    if (pos0) {
        locv += smoothl1(((const float4*)bbox)[base + a0], sgcs[g0]);
        pcv += posbce(p0); npv += 1;
    } else {
        unsigned bin = __float_as_uint(negloss(p0)) >> 20;
        atomicAdd(&hist[bin & 2047u], 1u << ((bin >> 11) << 4));
    }
    if (pos1) {
        locv += smoothl1(((const float4*)bbox)[base + a1], sgcs[g1]);
        pcv += posbce(p1); npv += 1;
    } else {
        unsigned bin = __float_as_uint(negloss(p1)) >> 20;
        atomicAdd(&hist[bin & 2047u], 1u << ((bin >> 11) << 4));
    }

    for (int off = 32; off; off >>= 1) {
        locv += __shfl_xor(locv, off);
        pcv  += __shfl_xor(pcv, off);
        npv  += __shfl_xor(npv, off);
    }
    if (lane == 0) { redL[wave] = locv; redP[wave] = pcv; redN[wave] = npv; }
    __syncthreads();
    if (tid == 0) {
        float L = redL[0] + redL[1] + redL[2] + redL[3];
        float P = redP[0] + redP[1] + redP[2] + redP[3];
        int   N = redN[0] + redN[1] + redN[2] + redN[3];
        if (N) atomicAdd(&num_pos[b], N);
        atomicAdd(&locs[b], L);
        atomicAdd(&pcs[b], P);
    }
    // flush packed hist -> global 4096-bin u32 hist1 (exact counts)
    for (int i = tid; i < 2048; i += TPB) {
        unsigned w = hist[i];
        unsigned c0 = w & 0xFFFFu, c1 = w >> 16;
        if (c0) atomicAdd(&hist1[b * 4096 + i], c0);
        if (c1) atomicAdd(&hist1[b * 4096 + i + 2048], c1);
    }
}

// ===================== k_scan: distributed tail (r16, unchanged) =====================
__global__ __launch_bounds__(1024) void k_scan(const float* __restrict__ bbox,
                                               const float* __restrict__ conf,
                                               const float* __restrict__ gt,
                                               const unsigned char* __restrict__ abyte,
                                               const unsigned long long* __restrict__ gkey,
                                               const unsigned* __restrict__ hist1,
                                               const int* __restrict__ num_pos,
                                               int* __restrict__ totN,
                                               float* __restrict__ totL,
                                               float* __restrict__ totPC,
                                               float* __restrict__ negacc,
                                               unsigned* __restrict__ scnt,
                                               uint2* __restrict__ selinfo,
                                               int* __restrict__ fnum,
                                               float* __restrict__ surv) {
    __shared__ unsigned hist[4096];     // 16 KB
    __shared__ float scomp[4096];       // 16 KB survivor staging
    __shared__ unsigned bitmap[128];
    __shared__ float4 sgcs[GN];
    __shared__ unsigned sforced[GN];
    __shared__ float redA[16];
    __shared__ unsigned s_c, s_base, s_sel, s_krem, s_k;

    int blk = blockIdx.x, b = blockIdx.y, tid = threadIdx.x;
    int lane = tid & 63, wave = tid >> 6;

    for (int i = tid; i < 4096; i += 1024) hist[i] = hist1[b * 4096 + i];
    if (tid < 128) bitmap[tid] = 0;
    if (tid == 0) s_c = 0;
    if (tid < GN) {
        float4 g = ((const float4*)gt)[b * GN + tid];
        sgcs[tid] = make_float4((g.x + g.z) * 0.5f, (g.y + g.w) * 0.5f,
                                g.z - g.x, g.w - g.y);
    }
    __syncthreads();

    if (tid < GN) {
        unsigned a = ~(unsigned)(gkey[b * GN + tid] & 0xFFFFFFFFull);
        sforced[tid] = a;
        if ((int)(a >> 12) == blk)
            atomicOr(&bitmap[(a & 4095u) >> 5], 1u << (a & 31u));
    }
    __syncthreads();

    // forced corrections + np + k (wave 0; deterministic, redundant per block)
    if (tid < GN) {
        unsigned a = sforced[tid];
        bool own = true;
        for (int t = 0; t < tid; ++t) if (sforced[t] == a) { own = false; break; }
        int fn = 0; float fl = 0.0f, fp = 0.0f;
        if (own) {
            unsigned by = abyte[(size_t)b * AN + a];
            if (!(by & 0x80u)) {
                float p = conf[(size_t)b * AN + a];
                atomicAdd(&hist[__float_as_uint(negloss(p)) >> 20], 0xFFFFFFFFu);
                fn = 1; fp = posbce(p);
                fl = smoothl1(((const float4*)bbox)[(size_t)b * AN + a], sgcs[by & 63u]);
            }
        }
        for (int off = 32; off; off >>= 1) {
            fn += __shfl_xor(fn, off);
            fl += __shfl_xor(fl, off);
            fp += __shfl_xor(fp, off);
        }
        int np = num_pos[b] + fn;
        unsigned k = (unsigned)min(3 * np, AN - np);
        if (tid == 0) {
            s_k = k;
            if (blk == 0) {
                fnum[b] = fn;
                if (fn) atomicAdd(totN, fn);
                atomicAdd(totL, fl);
                atomicAdd(totPC, fp);
            }
        }
    }
    __syncthreads();
    unsigned k = s_k;
    if (k == 0) return;                    // negacc/scnt stay 0

    // round-1 select over corrected hist (two-level wave scan)
    if (tid < 64) {
        unsigned c = 0;
        int base = tid * 64;
#pragma unroll
        for (int i = 0; i < 64; ++i) c += hist[base + ((tid + i) & 63)];   // rotated
        unsigned S = c;
#pragma unroll
        for (int d = 1; d < 64; d <<= 1) { unsigned t = __shfl_down(S, d); if (tid + d < 64) S += t; }
        unsigned E = S - c;
        unsigned long long mk = __ballot(E < k && k <= S);
        int bl = __ffsll(mk) - 1;
        unsigned kin = k - __shfl(E, bl);
        unsigned h = hist[bl * 64 + tid];
        unsigned S2 = h;
#pragma unroll
        for (int d = 1; d < 64; d <<= 1) { unsigned t = __shfl_down(S2, d); if (tid + d < 64) S2 += t; }
        unsigned E2 = S2 - h;
        unsigned long long mk2 = __ballot(E2 < kin && kin <= S2);
        int bin_l = __ffsll(mk2) - 1;
        unsigned E2b = __shfl(E2, bin_l);
        if (tid == 0) { s_sel = (unsigned)(bl * 64 + bin_l); s_krem = kin - E2b; }
    }
    __syncthreads();
    unsigned sel1 = s_sel;
    if (blk == 0 && tid == 0) selinfo[b] = make_uint2(s_sel, s_krem);

    // stream own 4096 anchors: strictly-above sum + boundary compaction
    size_t ibase = (size_t)b * AN + blk * 4096;
    float4 c4 = ((const float4*)conf)[(ibase >> 2) + tid];
    uchar4 u4 = ((const uchar4*)abyte)[(ibase >> 2) + tid];
    int li = tid * 4;
    unsigned fb = (bitmap[li >> 5] >> (li & 31)) & 0xFu;
    float cc[4] = {c4.x, c4.y, c4.z, c4.w};
    unsigned by[4] = {u4.x, u4.y, u4.z, u4.w};
    float acc = 0.0f;
#pragma unroll
    for (int e = 0; e < 4; ++e) {
        bool pos = (by[e] & 0x80u) || ((fb >> e) & 1u);
        if (!pos) {
            float v = negloss(cc[e]);
            unsigned bin = __float_as_uint(v) >> 20;
            if (bin > sel1) acc += v;
            else if (bin == sel1) {
                unsigned p = atomicAdd(&s_c, 1u);   // LDS atomic
                scomp[p] = v;                        // <=4096 per block
            }
        }
    }
    for (int off = 32; off; off >>= 1) acc += __shfl_xor(acc, off);
    if (lane == 0) redA[wave] = acc;
    __syncthreads();
    if (tid == 0) {
        float t = 0.0f;
        for (int w = 0; w < 16; ++w) t += redA[w];
        atomicAdd(&negacc[b], t);
        s_base = atomicAdd(&scnt[b], s_c);          // one reservation per block
    }
    __syncthreads();
    unsigned cnt = s_c, base2 = s_base;
    for (unsigned i = tid; i < cnt; i += 1024)
        if (base2 + i < CAP) surv[(size_t)b * CAP + base2 + i] = scomp[i];
}

// ===================== k_fin: resolve low 20 bits + finalize (r16, unchanged) =====================
__global__ __launch_bounds__(1024) void k_fin(const float* __restrict__ surv,
                                              const unsigned* __restrict__ scnt,
                                              const uint2* __restrict__ selinfo,
                                              const int* __restrict__ num_pos,
                                              const int* __restrict__ fnum,
                                              const float* __restrict__ locs,
                                              const float* __restrict__ pcs,
                                              const float* __restrict__ negacc,
                                              int* __restrict__ totN,
                                              float* __restrict__ totL,
                                              float* __restrict__ totPC,
                                              unsigned* __restrict__ done,
                                              float* __restrict__ out) {
    __shared__ float sv[CAP];           // 32 KB
    __shared__ unsigned hist[4096];     // 16 KB
    __shared__ float redA[16];
    __shared__ unsigned s_sel, s_krem;

    int b = blockIdx.x, tid = threadIdx.x;
    int lane = tid & 63, wave = tid >> 6;

    int np = num_pos[b] + fnum[b];
    unsigned k = (unsigned)min(3 * np, AN - np);
    float nc = 0.0f;

    if (k > 0) {
        uint2 si = selinfo[b];
        unsigned krem1 = si.y;
        unsigned n = min(scnt[b], (unsigned)CAP);
        for (unsigned i = tid; i < n; i += 1024) sv[i] = surv[(size_t)b * CAP + i];
        for (int i = tid; i < 4096; i += 1024) hist[i] = 0;
        __syncthreads();

        // round A: 12 bits (key>>8)&0xFFF
        for (unsigned i = tid; i < n; i += 1024)
            atomicAdd(&hist[(__float_as_uint(sv[i]) >> 8) & 0xFFFu], 1u);
        __syncthreads();
        if (tid < 64) {
            unsigned c = 0;
            int base = tid * 64;
#pragma unroll
            for (int i = 0; i < 64; ++i) c += hist[base + ((tid + i) & 63)];
            unsigned S = c;
#pragma unroll
            for (int d = 1; d < 64; d <<= 1) { unsigned t = __shfl_down(S, d); if (tid + d < 64) S += t; }
            unsigned E = S - c;
            unsigned long long mk = __ballot(E < krem1 && krem1 <= S);
            int bl = __ffsll(mk) - 1;
            unsigned kin = krem1 - __shfl(E, bl);
            unsigned h = hist[bl * 64 + tid];
            unsigned S2 = h;
#pragma unroll
            for (int d = 1; d < 64; d <<= 1) { unsigned t = __shfl_down(S2, d); if (tid + d < 64) S2 += t; }
            unsigned E2 = S2 - h;
            unsigned long long mk2 = __ballot(E2 < kin && kin <= S2);
            int bin_l = __ffsll(mk2) - 1;
            unsigned E2b = __shfl(E2, bin_l);
            if (tid == 0) { s_sel = (unsigned)(bl * 64 + bin_l); s_krem = kin - E2b; }
        }
        __syncthreads();
        unsigned selA = s_sel, krem2 = s_krem;
        __syncthreads();
        if (tid < 256) hist[tid] = 0;
        __syncthreads();

        // round B: low 8 bits, masked to selA
        for (unsigned i = tid; i < n; i += 1024) {
            unsigned key = __float_as_uint(sv[i]);
            if (((key >> 8) & 0xFFFu) == selA) atomicAdd(&hist[key & 0xFFu], 1u);
        }
        __syncthreads();
        if (tid < 64) {
            int base = tid * 4;
            unsigned c = 0;
#pragma unroll
            for (int i = 0; i < 4; ++i) c += hist[base + i];
            unsigned S = c;
#pragma unroll
            for (int d = 1; d < 64; d <<= 1) { unsigned t = __shfl_down(S, d); if (tid + d < 64) S += t; }
            unsigned E = S - c;
            unsigned long long mk = __ballot(E < krem2 && krem2 <= S);
            int bl = __ffsll(mk) - 1;
            if (tid == bl) {
                unsigned cum = E;
                for (int bin = base + 3; bin >= base; --bin) {
                    unsigned h = hist[bin];
                    cum += h;
                    if (cum >= krem2) { s_sel = (unsigned)bin; s_krem = krem2 - (cum - h); break; }
                }
            }
        }
        __syncthreads();
        unsigned Tkey = (si.x << 20) | (selA << 8) | s_sel;
        unsigned kremF = s_krem;
        float T = __uint_as_float(Tkey);

        float part = 0.0f;
        for (unsigned i = tid; i < n; i += 1024)
            if (__float_as_uint(sv[i]) > Tkey) part += sv[i];
        for (int off = 32; off; off >>= 1) part += __shfl_xor(part, off);
        if (lane == 0) redA[wave] = part;
        __syncthreads();
        if (tid == 0) {
            float t = 0.0f;
            for (int w = 0; w < 16; ++w) t += redA[w];
            nc = negacc[b] + t + (float)kremF * T;
        }
    }

    if (tid == 0) {
        atomicAdd(totN, num_pos[b]);        // fn was added by k_scan blk0
        atomicAdd(totL, locs[b]);
        atomicAdd(totPC, pcs[b] + nc);
        __threadfence();
        unsigned old = atomicAdd(done, 1u);
        if (old == BN - 1) {
            int   N  = atomicAdd(totN, 0);
            float L  = atomicAdd(totL, 0.0f);
            float PC = atomicAdd(totPC, 0.0f);
            float tp = (float)max(1, N);
            float loc_loss = L / tp;
            float conf_loss = PC / tp;
            out[0] = loc_loss + conf_loss;
            out[1] = conf_loss;
            out[2] = loc_loss;
        }
    }
}

extern "C" void kernel_launch(void* const* d_in, const int* in_sizes, int n_in,
                              void* d_out, int out_size, void* d_ws, size_t ws_size,
                              hipStream_t stream) {
    const float* bbox    = (const float*)d_in[0];   // [B,A,4]
    const float* conf    = (const float*)d_in[1];   // [B,A]
    const float* anchors = (const float*)d_in[2];   // [A,4]
    const float* gt      = (const float*)d_in[3];   // [B,G,4]
    float* out = (float*)d_out;

    k_init<<<128, 256, 0, stream>>>((unsigned*)d_ws);

    dim3 g1(FBLK, BN);                // (64, 32) -> fully resident (8 blocks/CU)
    k_fused<<<g1, TPB, 0, stream>>>(anchors, gt, bbox, conf,
                                    WS_GKEY(d_ws), WS_ABYTE(d_ws), WS_HIST1(d_ws),
                                    WS_NUMPOS(d_ws), WS_LOCS(d_ws), WS_PCS(d_ws));

    dim3 g2(SBLK, BN);                // 256 blocks
    k_scan<<<g2, 1024, 0, stream>>>(bbox, conf, gt, WS_ABYTE(d_ws), WS_GKEY(d_ws),
                                    WS_HIST1(d_ws), WS_NUMPOS(d_ws),
                                    WS_TOTN(d_ws), WS_TOTL(d_ws), WS_TOTPC(d_ws),
                                    WS_NEGACC(d_ws), WS_SCNT(d_ws), WS_SELINFO(d_ws),
                                    WS_FNUM(d_ws), WS_SURV(d_ws));

    k_fin<<<BN, 1024, 0, stream>>>(WS_SURV(d_ws), WS_SCNT(d_ws), WS_SELINFO(d_ws),
                                   WS_NUMPOS(d_ws), WS_FNUM(d_ws), WS_LOCS(d_ws),
                                   WS_PCS(d_ws), WS_NEGACC(d_ws),
                                   WS_TOTN(d_ws), WS_TOTL(d_ws), WS_TOTPC(d_ws),
                                   WS_DONE(d_ws), out);
}

// Round 19
// 67.359 us; speedup vs baseline: 1.4142x; 1.0126x over previous
//
#include <hip/hip_runtime.h>
#include <cmath>

#define BN 32
#define AN 32768
#define GN 64
#define TPB 256                    // k_fused threads per block
#define ANCH_PER_BLK 512           // 2 anchors per thread
#define FBLK 64                    // k_fused blocks per image
#define SBLK 8                     // k_scan blocks per image
#define CAP 8192                   // survivor capacity per image

// ---------------- workspace layout (bytes) ----------------
// 0    : int totN ; 4: float totL ; 8: float totPC ; 12: uint done
// 64   : int   num_pos[32]   (bit7-positives only)
// 192  : float locs[32]
// 320  : float pcs[32]
// 448  : float negacc[32]
// 576  : uint  scnt[32]
// 704  : int   fnum[32]
// 832  : uint2 selinfo[32]
// 1280 : u64   gkey[B*G]        (16 KB, atomicMax)
// 17664   : u32 hist1[B][4096]  (512 KB, atomicAdd)
// 541952  : u8  abyte[B*A]      (1 MB, fully overwritten)
// 1590528 : f32 surv[B][CAP]    (1 MB, gated by scnt)
#define WS_TOTN(ws)    ((int*)(ws))
#define WS_TOTL(ws)    ((float*)((char*)(ws) + 4))
#define WS_TOTPC(ws)   ((float*)((char*)(ws) + 8))
#define WS_DONE(ws)    ((unsigned*)((char*)(ws) + 12))
#define WS_NUMPOS(ws)  ((int*)((char*)(ws) + 64))
#define WS_LOCS(ws)    ((float*)((char*)(ws) + 192))
#define WS_PCS(ws)     ((float*)((char*)(ws) + 320))
#define WS_NEGACC(ws)  ((float*)((char*)(ws) + 448))
#define WS_SCNT(ws)    ((unsigned*)((char*)(ws) + 576))
#define WS_FNUM(ws)    ((int*)((char*)(ws) + 704))
#define WS_SELINFO(ws) ((uint2*)((char*)(ws) + 832))
#define WS_GKEY(ws)    ((unsigned long long*)((char*)(ws) + 1280))
#define WS_HIST1(ws)   ((unsigned*)((char*)(ws) + 17664))
#define WS_ABYTE(ws)   ((unsigned char*)((char*)(ws) + 541952))
#define WS_SURV(ws)    ((float*)((char*)(ws) + 1590528))
#define WS_ZERO_WORDS  (541952 / 4)     // scalars + gkey + hist1

#define LN2F 0.69314718056f

__device__ __forceinline__ float negloss(float p) {
    // -log(1-p); MUST be bit-identical in every kernel (histogram bins).
    return -fmaxf(__log2f(1.0f - p) * LN2F, -100.0f);
}
__device__ __forceinline__ float posbce(float p) {
    return -fmaxf(__log2f(p) * LN2F, -100.0f);
}
__device__ __forceinline__ float smoothl1(float4 bb, float4 m) {
    float d0 = (bb.x + bb.z) * 0.5f - m.x;
    float d1 = (bb.y + bb.w) * 0.5f - m.y;
    float d2 = (bb.z - bb.x) - m.z;
    float d3 = (bb.w - bb.y) - m.w;
    float ad = fabsf(d0); float s = (ad < 1.0f) ? 0.5f * d0 * d0 : ad - 0.5f;
    ad = fabsf(d1); s += (ad < 1.0f) ? 0.5f * d1 * d1 : ad - 0.5f;
    ad = fabsf(d2); s += (ad < 1.0f) ? 0.5f * d2 * d2 : ad - 0.5f;
    ad = fabsf(d3); s += (ad < 1.0f) ? 0.5f * d3 * d3 : ad - 0.5f;
    return s;
}

// ===================== k_init =====================
__global__ __launch_bounds__(256) void k_init(unsigned* __restrict__ ws) {
    unsigned gid = blockIdx.x * 256 + threadIdx.x;
    for (unsigned i = gid; i < WS_ZERO_WORDS; i += 128 * 256) ws[i] = 0u;
}

// ===================== k_fused: IoU + argmaxes + prep (r16 proven) =====================
//  (a) corners packed float4 -> 1 ds_read_b128 per j;
//  (b) hist packed 2x u16 per u32 word -> 8 KB LDS; total ~13 KB -> 8 blocks/CU.
__global__ __launch_bounds__(TPB, 8) void k_fused(const float* __restrict__ anchors,
                                                  const float* __restrict__ gt,
                                                  const float* __restrict__ bbox,
                                                  const float* __restrict__ conf,
                                                  unsigned long long* __restrict__ gkey,
                                                  unsigned char* __restrict__ abyte,
                                                  unsigned* __restrict__ hist1,
                                                  int* __restrict__ num_pos,
                                                  float* __restrict__ locs,
                                                  float* __restrict__ pcs) {
    __shared__ float4 sgt4[128];                 // duplicated corners (16B aligned)
    __shared__ float  sga[128];                  // duplicated areas
    __shared__ float4 sgcs[GN];
    __shared__ unsigned long long skey2[128];    // flat, idx-addressed
    __shared__ unsigned hist[2048];              // 8 KB: bins i and i+2048 packed u16
    __shared__ float redL[4], redP[4];
    __shared__ int   redN[4];

    int b = blockIdx.y;
    int tid = threadIdx.x;
    int lane = tid & 63;
    int wave = tid >> 6;
    int blockbase = blockIdx.x * ANCH_PER_BLK;

    for (int i = tid; i < 2048; i += TPB) hist[i] = 0;
    if (tid < GN) {
        float4 g = ((const float4*)gt)[b * GN + tid];
        float area = (g.z - g.x) * (g.w - g.y);
        sgt4[tid] = g; sgt4[tid + 64] = g;
        sga[tid]  = area; sga[tid + 64] = area;
        sgcs[tid] = make_float4((g.x + g.z) * 0.5f, (g.y + g.w) * 0.5f,
                                g.z - g.x, g.w - g.y);
        skey2[tid] = 0ull; skey2[tid + 64] = 0ull;
    }
    __syncthreads();

    unsigned a0 = (unsigned)(blockbase + tid);
    unsigned a1 = a0 + TPB;
    float4 ab0 = ((const float4*)anchors)[a0];
    float4 ab1 = ((const float4*)anchors)[a1];
    float sa0 = (ab0.z - ab0.x) * (ab0.w - ab0.y) + 1e-6f;
    float sa1 = (ab1.z - ab1.x) * (ab1.w - ab1.y) + 1e-6f;
    unsigned na0 = ~a0, na1 = ~a1;

    float bv0 = -1.0f, bv1 = -1.0f;
    int bi0 = 0, bi1 = 0;

#pragma unroll 8
    for (int j = 0; j < GN; ++j) {
        int idx = lane + j;                  // 0..126, duplicated tables (no wrap)
        float4 gq = sgt4[idx];               // 1 x ds_read_b128
        float gA  = sga[idx];                // 1 x ds_read_b32

        float iw0 = fminf(ab0.z, gq.z) - fmaxf(ab0.x, gq.x);
        float ih0 = fminf(ab0.w, gq.w) - fmaxf(ab0.y, gq.y);
        float in0 = fmaxf(iw0, 0.0f) * fmaxf(ih0, 0.0f);
        float v0 = in0 * __builtin_amdgcn_rcpf((sa0 + gA) - in0);

        float iw1 = fminf(ab1.z, gq.z) - fmaxf(ab1.x, gq.x);
        float ih1 = fminf(ab1.w, gq.w) - fmaxf(ab1.y, gq.y);
        float in1 = fmaxf(iw1, 0.0f) * fmaxf(ih1, 0.0f);
        float v1 = in1 * __builtin_amdgcn_rcpf((sa1 + gA) - in1);

        if (v0 > bv0) { bv0 = v0; bi0 = idx; }
        if (v1 > bv1) { bv1 = v1; bi1 = idx; }

        float vm = v0; unsigned nam = na0;           // a0 < a1: min idx on ties
        if (v1 > vm) { vm = v1; nam = na1; }
        unsigned long long key = ((unsigned long long)__float_as_uint(vm) << 32)
                               | (unsigned long long)nam;
        atomicMax(&skey2[idx], key);                 // imm-offset ds_max under unroll
    }
    __syncthreads();

    size_t base = (size_t)b * AN;
    unsigned g0 = (unsigned)bi0 & 63u, g1 = (unsigned)bi1 & 63u;
    bool pos0 = bv0 > 0.5f, pos1 = bv1 > 0.5f;
    abyte[base + a0] = (unsigned char)((pos0 ? 0x80u : 0u) | g0);
    abyte[base + a1] = (unsigned char)((pos1 ? 0x80u : 0u) | g1);

    if (tid < GN) {
        unsigned long long m0 = skey2[tid];
        unsigned long long m1 = skey2[tid + 64];     // same gt, rotated wrap half
        atomicMax(&gkey[b * GN + tid], (m0 > m1) ? m0 : m1);
    }

    // ---- prep: conf, pos scalars, negloss hist (packed u16 pairs)
    float p0 = conf[base + a0];
    float p1 = conf[base + a1];
    float locv = 0.0f, pcv = 0.0f;
    int npv = 0;
    if (pos0) {
        locv += smoothl1(((const float4*)bbox)[base + a0], sgcs[g0]);
        pcv += posbce(p0); npv += 1;
    } else {
        unsigned bin = __float_as_uint(negloss(p0)) >> 20;
        atomicAdd(&hist[bin & 2047u], 1u << ((bin >> 11) << 4));
    }
    if (pos1) {
        locv += smoothl1(((const float4*)bbox)[base + a1], sgcs[g1]);
        pcv += posbce(p1); npv += 1;
    } else {
        unsigned bin = __float_as_uint(negloss(p1)) >> 20;
        atomicAdd(&hist[bin & 2047u], 1u << ((bin >> 11) << 4));
    }

    for (int off = 32; off; off >>= 1) {
        locv += __shfl_xor(locv, off);
        pcv  += __shfl_xor(pcv, off);
        npv  += __shfl_xor(npv, off);
    }
    if (lane == 0) { redL[wave] = locv; redP[wave] = pcv; redN[wave] = npv; }
    __syncthreads();
    if (tid == 0) {
        float L = redL[0] + redL[1] + redL[2] + redL[3];
        float P = redP[0] + redP[1] + redP[2] + redP[3];
        int   N = redN[0] + redN[1] + redN[2] + redN[3];
        if (N) atomicAdd(&num_pos[b], N);
        atomicAdd(&locs[b], L);
        atomicAdd(&pcs[b], P);
    }
    // flush packed hist -> global 4096-bin u32 hist1 (exact counts)
    for (int i = tid; i < 2048; i += TPB) {
        unsigned w = hist[i];
        unsigned c0 = w & 0xFFFFu, c1 = w >> 16;
        if (c0) atomicAdd(&hist1[b * 4096 + i], c0);
        if (c1) atomicAdd(&hist1[b * 4096 + i + 2048], c1);
    }
}

// ===================== k_scan: distributed tail (r16, unchanged) =====================
__global__ __launch_bounds__(1024) void k_scan(const float* __restrict__ bbox,
                                               const float* __restrict__ conf,
                                               const float* __restrict__ gt,
                                               const unsigned char* __restrict__ abyte,
                                               const unsigned long long* __restrict__ gkey,
                                               const unsigned* __restrict__ hist1,
                                               const int* __restrict__ num_pos,
                                               int* __restrict__ totN,
                                               float* __restrict__ totL,
                                               float* __restrict__ totPC,
                                               float* __restrict__ negacc,
                                               unsigned* __restrict__ scnt,
                                               uint2* __restrict__ selinfo,
                                               int* __restrict__ fnum,
                                               float* __restrict__ surv) {
    __shared__ unsigned hist[4096];     // 16 KB
    __shared__ float scomp[4096];       // 16 KB survivor staging
    __shared__ unsigned bitmap[128];
    __shared__ float4 sgcs[GN];
    __shared__ unsigned sforced[GN];
    __shared__ float redA[16];
    __shared__ unsigned s_c, s_base, s_sel, s_krem, s_k;

    int blk = blockIdx.x, b = blockIdx.y, tid = threadIdx.x;
    int lane = tid & 63, wave = tid >> 6;

    for (int i = tid; i < 4096; i += 1024) hist[i] = hist1[b * 4096 + i];
    if (tid < 128) bitmap[tid] = 0;
    if (tid == 0) s_c = 0;
    if (tid < GN) {
        float4 g = ((const float4*)gt)[b * GN + tid];
        sgcs[tid] = make_float4((g.x + g.z) * 0.5f, (g.y + g.w) * 0.5f,
                                g.z - g.x, g.w - g.y);
    }
    __syncthreads();

    if (tid < GN) {
        unsigned a = ~(unsigned)(gkey[b * GN + tid] & 0xFFFFFFFFull);
        sforced[tid] = a;
        if ((int)(a >> 12) == blk)
            atomicOr(&bitmap[(a & 4095u) >> 5], 1u << (a & 31u));
    }
    __syncthreads();

    // forced corrections + np + k (wave 0; deterministic, redundant per block)
    if (tid < GN) {
        unsigned a = sforced[tid];
        bool own = true;
        for (int t = 0; t < tid; ++t) if (sforced[t] == a) { own = false; break; }
        int fn = 0; float fl = 0.0f, fp = 0.0f;
        if (own) {
            unsigned by = abyte[(size_t)b * AN + a];
            if (!(by & 0x80u)) {
                float p = conf[(size_t)b * AN + a];
                atomicAdd(&hist[__float_as_uint(negloss(p)) >> 20], 0xFFFFFFFFu);
                fn = 1; fp = posbce(p);
                fl = smoothl1(((const float4*)bbox)[(size_t)b * AN + a], sgcs[by & 63u]);
            }
        }
        for (int off = 32; off; off >>= 1) {
            fn += __shfl_xor(fn, off);
            fl += __shfl_xor(fl, off);
            fp += __shfl_xor(fp, off);
        }
        int np = num_pos[b] + fn;
        unsigned k = (unsigned)min(3 * np, AN - np);
        if (tid == 0) {
            s_k = k;
            if (blk == 0) {
                fnum[b] = fn;
                if (fn) atomicAdd(totN, fn);
                atomicAdd(totL, fl);
                atomicAdd(totPC, fp);
            }
        }
    }
    __syncthreads();
    unsigned k = s_k;
    if (k == 0) return;                    // negacc/scnt stay 0

    // round-1 select over corrected hist (two-level wave scan)
    if (tid < 64) {
        unsigned c = 0;
        int base = tid * 64;
#pragma unroll
        for (int i = 0; i < 64; ++i) c += hist[base + ((tid + i) & 63)];   // rotated
        unsigned S = c;
#pragma unroll
        for (int d = 1; d < 64; d <<= 1) { unsigned t = __shfl_down(S, d); if (tid + d < 64) S += t; }
        unsigned E = S - c;
        unsigned long long mk = __ballot(E < k && k <= S);
        int bl = __ffsll(mk) - 1;
        unsigned kin = k - __shfl(E, bl);
        unsigned h = hist[bl * 64 + tid];
        unsigned S2 = h;
#pragma unroll
        for (int d = 1; d < 64; d <<= 1) { unsigned t = __shfl_down(S2, d); if (tid + d < 64) S2 += t; }
        unsigned E2 = S2 - h;
        unsigned long long mk2 = __ballot(E2 < kin && kin <= S2);
        int bin_l = __ffsll(mk2) - 1;
        unsigned E2b = __shfl(E2, bin_l);
        if (tid == 0) { s_sel = (unsigned)(bl * 64 + bin_l); s_krem = kin - E2b; }
    }
    __syncthreads();
    unsigned sel1 = s_sel;
    if (blk == 0 && tid == 0) selinfo[b] = make_uint2(s_sel, s_krem);

    // stream own 4096 anchors: strictly-above sum + boundary compaction
    size_t ibase = (size_t)b * AN + blk * 4096;
    float4 c4 = ((const float4*)conf)[(ibase >> 2) + tid];
    uchar4 u4 = ((const uchar4*)abyte)[(ibase >> 2) + tid];
    int li = tid * 4;
    unsigned fb = (bitmap[li >> 5] >> (li & 31)) & 0xFu;
    float cc[4] = {c4.x, c4.y, c4.z, c4.w};
    unsigned by[4] = {u4.x, u4.y, u4.z, u4.w};
    float acc = 0.0f;
#pragma unroll
    for (int e = 0; e < 4; ++e) {
        bool pos = (by[e] & 0x80u) || ((fb >> e) & 1u);
        if (!pos) {
            float v = negloss(cc[e]);
            unsigned bin = __float_as_uint(v) >> 20;
            if (bin > sel1) acc += v;
            else if (bin == sel1) {
                unsigned p = atomicAdd(&s_c, 1u);   // LDS atomic
                scomp[p] = v;                        // <=4096 per block
            }
        }
    }
    for (int off = 32; off; off >>= 1) acc += __shfl_xor(acc, off);
    if (lane == 0) redA[wave] = acc;
    __syncthreads();
    if (tid == 0) {
        float t = 0.0f;
        for (int w = 0; w < 16; ++w) t += redA[w];
        atomicAdd(&negacc[b], t);
        s_base = atomicAdd(&scnt[b], s_c);          // one reservation per block
    }
    __syncthreads();
    unsigned cnt = s_c, base2 = s_base;
    for (unsigned i = tid; i < cnt; i += 1024)
        if (base2 + i < CAP) surv[(size_t)b * CAP + base2 + i] = scomp[i];
}

// ===================== k_fin: resolve low 20 bits + finalize (r16, unchanged) =====================
__global__ __launch_bounds__(1024) void k_fin(const float* __restrict__ surv,
                                              const unsigned* __restrict__ scnt,
                                              const uint2* __restrict__ selinfo,
                                              const int* __restrict__ num_pos,
                                              const int* __restrict__ fnum,
                                              const float* __restrict__ locs,
                                              const float* __restrict__ pcs,
                                              const float* __restrict__ negacc,
                                              int* __restrict__ totN,
                                              float* __restrict__ totL,
                                              float* __restrict__ totPC,
                                              unsigned* __restrict__ done,
                                              float* __restrict__ out) {
    __shared__ float sv[CAP];           // 32 KB
    __shared__ unsigned hist[4096];     // 16 KB
    __shared__ float redA[16];
    __shared__ unsigned s_sel, s_krem;

    int b = blockIdx.x, tid = threadIdx.x;
    int lane = tid & 63, wave = tid >> 6;

    int np = num_pos[b] + fnum[b];
    unsigned k = (unsigned)min(3 * np, AN - np);
    float nc = 0.0f;

    if (k > 0) {
        uint2 si = selinfo[b];
        unsigned krem1 = si.y;
        unsigned n = min(scnt[b], (unsigned)CAP);
        for (unsigned i = tid; i < n; i += 1024) sv[i] = surv[(size_t)b * CAP + i];
        for (int i = tid; i < 4096; i += 1024) hist[i] = 0;
        __syncthreads();

        // round A: 12 bits (key>>8)&0xFFF
        for (unsigned i = tid; i < n; i += 1024)
            atomicAdd(&hist[(__float_as_uint(sv[i]) >> 8) & 0xFFFu], 1u);
        __syncthreads();
        if (tid < 64) {
            unsigned c = 0;
            int base = tid * 64;
#pragma unroll
            for (int i = 0; i < 64; ++i) c += hist[base + ((tid + i) & 63)];
            unsigned S = c;
#pragma unroll
            for (int d = 1; d < 64; d <<= 1) { unsigned t = __shfl_down(S, d); if (tid + d < 64) S += t; }
            unsigned E = S - c;
            unsigned long long mk = __ballot(E < krem1 && krem1 <= S);
            int bl = __ffsll(mk) - 1;
            unsigned kin = krem1 - __shfl(E, bl);
            unsigned h = hist[bl * 64 + tid];
            unsigned S2 = h;
#pragma unroll
            for (int d = 1; d < 64; d <<= 1) { unsigned t = __shfl_down(S2, d); if (tid + d < 64) S2 += t; }
            unsigned E2 = S2 - h;
            unsigned long long mk2 = __ballot(E2 < kin && kin <= S2);
            int bin_l = __ffsll(mk2) - 1;
            unsigned E2b = __shfl(E2, bin_l);
            if (tid == 0) { s_sel = (unsigned)(bl * 64 + bin_l); s_krem = kin - E2b; }
        }
        __syncthreads();
        unsigned selA = s_sel, krem2 = s_krem;
        __syncthreads();
        if (tid < 256) hist[tid] = 0;
        __syncthreads();

        // round B: low 8 bits, masked to selA
        for (unsigned i = tid; i < n; i += 1024) {
            unsigned key = __float_as_uint(sv[i]);
            if (((key >> 8) & 0xFFFu) == selA) atomicAdd(&hist[key & 0xFFu], 1u);
        }
        __syncthreads();
        if (tid < 64) {
            int base = tid * 4;
            unsigned c = 0;
#pragma unroll
            for (int i = 0; i < 4; ++i) c += hist[base + i];
            unsigned S = c;
#pragma unroll
            for (int d = 1; d < 64; d <<= 1) { unsigned t = __shfl_down(S, d); if (tid + d < 64) S += t; }
            unsigned E = S - c;
            unsigned long long mk = __ballot(E < krem2 && krem2 <= S);
            int bl = __ffsll(mk) - 1;
            if (tid == bl) {
                unsigned cum = E;
                for (int bin = base + 3; bin >= base; --bin) {
                    unsigned h = hist[bin];
                    cum += h;
                    if (cum >= krem2) { s_sel = (unsigned)bin; s_krem = krem2 - (cum - h); break; }
                }
            }
        }
        __syncthreads();
        unsigned Tkey = (si.x << 20) | (selA << 8) | s_sel;
        unsigned kremF = s_krem;
        float T = __uint_as_float(Tkey);

        float part = 0.0f;
        for (unsigned i = tid; i < n; i += 1024)
            if (__float_as_uint(sv[i]) > Tkey) part += sv[i];
        for (int off = 32; off; off >>= 1) part += __shfl_xor(part, off);
        if (lane == 0) redA[wave] = part;
        __syncthreads();
        if (tid == 0) {
            float t = 0.0f;
            for (int w = 0; w < 16; ++w) t += redA[w];
            nc = negacc[b] + t + (float)kremF * T;
        }
    }

    if (tid == 0) {
        atomicAdd(totN, num_pos[b]);        // fn was added by k_scan blk0
        atomicAdd(totL, locs[b]);
        atomicAdd(totPC, pcs[b] + nc);
        __threadfence();
        unsigned old = atomicAdd(done, 1u);
        if (old == BN - 1) {
            int   N  = atomicAdd(totN, 0);
            float L  = atomicAdd(totL, 0.0f);
            float PC = atomicAdd(totPC, 0.0f);
            float tp = (float)max(1, N);
            float loc_loss = L / tp;
            float conf_loss = PC / tp;
            out[0] = loc_loss + conf_loss;
            out[1] = conf_loss;
            out[2] = loc_loss;
        }
    }
}

extern "C" void kernel_launch(void* const* d_in, const int* in_sizes, int n_in,
                              void* d_out, int out_size, void* d_ws, size_t ws_size,
                              hipStream_t stream) {
    const float* bbox    = (const float*)d_in[0];   // [B,A,4]
    const float* conf    = (const float*)d_in[1];   // [B,A]
    const float* anchors = (const float*)d_in[2];   // [A,4]
    const float* gt      = (const float*)d_in[3];   // [B,G,4]
    float* out = (float*)d_out;

    k_init<<<128, 256, 0, stream>>>((unsigned*)d_ws);

    dim3 g1(FBLK, BN);                // (64, 32) -> fully resident (8 blocks/CU)
    k_fused<<<g1, TPB, 0, stream>>>(anchors, gt, bbox, conf,
                                    WS_GKEY(d_ws), WS_ABYTE(d_ws), WS_HIST1(d_ws),
                                    WS_NUMPOS(d_ws), WS_LOCS(d_ws), WS_PCS(d_ws));

    dim3 g2(SBLK, BN);                // 256 blocks
    k_scan<<<g2, 1024, 0, stream>>>(bbox, conf, gt, WS_ABYTE(d_ws), WS_GKEY(d_ws),
                                    WS_HIST1(d_ws), WS_NUMPOS(d_ws),
                                    WS_TOTN(d_ws), WS_TOTL(d_ws), WS_TOTPC(d_ws),
                                    WS_NEGACC(d_ws), WS_SCNT(d_ws), WS_SELINFO(d_ws),
                                    WS_FNUM(d_ws), WS_SURV(d_ws));

    k_fin<<<BN, 1024, 0, stream>>>(WS_SURV(d_ws), WS_SCNT(d_ws), WS_SELINFO(d_ws),
                                   WS_NUMPOS(d_ws), WS_FNUM(d_ws), WS_LOCS(d_ws),
                                   WS_PCS(d_ws), WS_NEGACC(d_ws),
                                   WS_TOTN(d_ws), WS_TOTL(d_ws), WS_TOTPC(d_ws),
                                   WS_DONE(d_ws), out);
}